// Round 1
// 107.489 us; speedup vs baseline: 1.0854x; 1.0854x over previous
//
#include <hip/hip_runtime.h>

// CIN fused 3-layer, bf16 MFMA, barrier-free K-loop (R7).
// cur[sl,n] = sum_f x_f[sl] * S_f[sl,n],  S_f = sum_g h_g[sl] * W[f*64+g, n].
//
// R7 changes vs R6 (53 us kernel, Occupancy 19.5%, MfmaUtil 22%):
//  - 2 batches/block (2 m-tiles, 32 slices) -> grid 512 -> 2 blocks/CU
//    co-resident (was 256 blocks = 1/CU, hard 25% occupancy cap).
//    Latency-bound kernel: doubles waves/SIMD 2->4.
//  - B-frag prefetch depth 2 -> 3 (c/m/n scalar pairs, #pragma unroll 3
//    over f=39 so rotation is pure renaming: no v_mov chains, no
//    runtime-indexed arrays -> no scratch).
//
// Wave w (0..7) owns n-tile w (16 channels) and both m-tiles (32 slices);
// B-frags streamed L2->VGPR with plain dwordx4 loads.
//
// wt layout (prep output), tile tl = l*39+f (layer0 g zero-padded):
//   wt[tl*8192 + ((ks*4 + q)*128 + n)*8 + j] = bf16(W_l[f*64 + ks*32+q*8+j][n])

#define NF     39
#define LCH    128
#define NLAYER 3
#define NFT    (NLAYER * NF)   // 117 f-tiles
#define BPB    2               // batches per block
#define SL     (BPB * 16)      // 32 slices per block
#define MT     (SL / 16)       // 2 m-tiles

typedef __bf16        bf16x8 __attribute__((ext_vector_type(8)));
typedef unsigned int  uint4v __attribute__((ext_vector_type(4)));
typedef float         f32x4  __attribute__((ext_vector_type(4)));

__device__ __forceinline__ unsigned short f2bf_rne(float f) {
    unsigned u = __float_as_uint(f);
    u += 0x7fffu + ((u >> 16) & 1u);
    return (unsigned short)(u >> 16);
}

// ---------------- prep: W fp32 -> bf16 frag-ready tiles in ws ----------------
__global__ void cin_prep(const float* __restrict__ W0,
                         const float* __restrict__ W1,
                         const float* __restrict__ W2,
                         unsigned short* __restrict__ wt)
{
    const int t = blockIdx.x * blockDim.x + threadIdx.x; // ((tl*2+ks)*4+q)*128 + n
    if (t >= NFT * 1024) return;
    const int n  = t & 127;
    const int q  = (t >> 7) & 3;
    const int ks = (t >> 9) & 1;
    const int tl = t >> 10;
    const int l  = tl / NF;
    const int f  = tl - l * NF;
    const float* W = (l == 0) ? W0 : (l == 1) ? W1 : W2;

    unsigned short v[8];
    #pragma unroll
    for (int j = 0; j < 8; ++j) {
        const int g = ks * 32 + q * 8 + j;
        float w = 0.0f;
        if (l == 0) { if (g < NF) w = W[(f * NF + g) * LCH + n]; }
        else        { w = W[(f * 64 + g) * LCH + n]; }
        v[j] = f2bf_rne(w);
    }
    uint4v pv;
    #pragma unroll
    for (int i = 0; i < 4; ++i)
        pv[i] = (unsigned)v[2 * i] | ((unsigned)v[2 * i + 1] << 16);
    ((uint4v*)wt)[t] = pv;   // 16B coalesced
}

// ---------------- main ----------------
__global__ __launch_bounds__(512, 4) void cin_mfma(
    const float* __restrict__ x,
    const unsigned short* __restrict__ wt,
    const float* __restrict__ b0p,
    const float* __restrict__ b1p,
    const float* __restrict__ b2p,
    float* __restrict__ out)
{
    __shared__ __align__(16) unsigned short hfrag[8 * SL * 8];  // [gblk][sl][j], 4 KB
    __shared__ float xf32[NF * SL];                             // [f][sl] fp32, ~4.9 KB
    __shared__ float biasl[NLAYER * LCH];

    const int tid  = threadIdx.x;
    const int lane = tid & 63;
    const int w    = tid >> 6;      // wave 0..7 = n-tile
    const int q    = lane >> 4;     // quad 0..3
    const int c    = lane & 15;
    const int nc   = w * 16 + c;    // this lane's output channel
    const int bb   = blockIdx.x * BPB;

    // zero hfrag (covers layer-0 padding g in [39,64)): 4 KB = 256 * 16B
    {
        f32x4 z4 = {0.f, 0.f, 0.f, 0.f};
        if (tid < (8 * SL * 8) / 8) ((f32x4*)hfrag)[tid] = z4;
    }
    for (int t = tid; t < NLAYER * LCH; t += 512)
        biasl[t] = (t < 128) ? b0p[t] : (t < 256) ? b1p[t - 128] : b2p[t - 256];
    __syncthreads();

    // stage x (contiguous BPB*NF*16 = 1248 floats for this block's batches)
    for (int i = tid; i < BPB * NF * 16; i += 512) {
        const float v = x[bb * (NF * 16) + i];
        const int lb = i / (NF * 16);
        const int r  = i - lb * (NF * 16);
        const int f  = r >> 4;
        const int d  = r & 15;
        const int sl = lb * 16 + d;
        xf32[f * SL + sl] = v;
        hfrag[((f >> 3) * SL + sl) * 8 + (f & 7)] = f2bf_rne(v);
    }

    // wave-private B pointer: lane (q,c) of wave w reads 16B at
    // wt + tl*8192 + (q*128 + nc)*8  (ks=0)  and +4096 shorts (ks=1)
    const unsigned short* wq = wt + (q * 128 + nc) * 8;

    // depth-3 rotation in plain scalars: c* = tile tl, m* = tl+1, n* = tl+2
    bf16x8 c0 = *(const bf16x8*)(wq);
    bf16x8 c1 = *(const bf16x8*)(wq + 4096);
    bf16x8 m0 = *(const bf16x8*)(wq + 8192);
    bf16x8 m1 = *(const bf16x8*)(wq + 8192 + 4096);
    bf16x8 n0 = *(const bf16x8*)(wq + 16384);
    bf16x8 n1 = *(const bf16x8*)(wq + 16384 + 4096);

    __syncthreads();   // x, hfrag, bias ready

    #pragma unroll 1
    for (int l = 0; l < NLAYER; ++l) {
        // hoist A-frags (h) for this layer: a[ks][mt] (literal indices only)
        bf16x8 a[2][MT];
        #pragma unroll
        for (int ks = 0; ks < 2; ++ks)
            #pragma unroll
            for (int mt = 0; mt < MT; ++mt)
                a[ks][mt] = *(const bf16x8*)&hfrag[((ks * 4 + q) * SL + mt * 16 + c) * 8];

        f32x4 cur[MT];
        #pragma unroll
        for (int mt = 0; mt < MT; ++mt) cur[mt] = f32x4{0.f, 0.f, 0.f, 0.f};
        const f32x4 z = {0.f, 0.f, 0.f, 0.f};

        #pragma unroll 3
        for (int f = 0; f < NF; ++f) {
            const bf16x8 bv0 = c0;
            const bf16x8 bv1 = c1;

            #pragma unroll
            for (int mt = 0; mt < MT; ++mt) {
                f32x4 sv = __builtin_amdgcn_mfma_f32_16x16x32_bf16(a[0][mt], bv0, z,  0, 0, 0);
                sv       = __builtin_amdgcn_mfma_f32_16x16x32_bf16(a[1][mt], bv1, sv, 0, 0, 0);
                const f32x4 xr = *(const f32x4*)&xf32[f * SL + mt * 16 + q * 4];
                #pragma unroll
                for (int r = 0; r < 4; ++r)
                    cur[mt][r] = fmaf(xr[r], sv[r], cur[mt][r]);
            }

            // rotate (pure renaming under unroll-3) and prefetch tl+3 (clamped)
            c0 = m0; c1 = m1;
            m0 = n0; m1 = n1;
            int pf = l * NF + f + 3; if (pf > NFT - 1) pf = NFT - 1;
            const unsigned short* p = wq + (size_t)pf * 8192;
            n0 = *(const bf16x8*)p;
            n1 = *(const bf16x8*)(p + 4096);
        }

        // ---------------- epilogue for layer l ----------------
        const float bias = biasl[l * LCH + nc];
        float v[MT][4];
        #pragma unroll
        for (int mt = 0; mt < MT; ++mt)
            #pragma unroll
            for (int r = 0; r < 4; ++r)
                v[mt][r] = fmaxf(cur[mt][r] + bias, 0.f);

        if (l < 2 && w < 4) {
            // h channels (nc < 64): write next layer's h (C row = q*4+r)
            #pragma unroll
            for (int mt = 0; mt < MT; ++mt)
                #pragma unroll
                for (int r = 0; r < 4; ++r)
                    hfrag[((nc >> 3) * SL + mt * 16 + q * 4 + r) * 8 + (nc & 7)] =
                        f2bf_rne(v[mt][r]);
        } else {
            // direct channels: reduce over d (= q*4+r) and store
            // l==0: nc 64..127 -> out 0..63 ; l==1: nc 64..127 -> out 64..127 ;
            // l==2: nc 0..127 -> out 128..255
            const int outcol = (l == 0) ? nc - 64 : (l == 1) ? nc : 128 + nc;
            #pragma unroll
            for (int mt = 0; mt < MT; ++mt) {
                float sacc = v[mt][0] + v[mt][1] + v[mt][2] + v[mt][3];
                sacc += __shfl_xor(sacc, 16, 64);
                sacc += __shfl_xor(sacc, 32, 64);
                if (lane < 16) out[(bb + mt) * 256 + outcol] = sacc;
            }
        }
        if (l < 2) __syncthreads();   // h writes visible before next A-hoist
    }
}

extern "C" void kernel_launch(void* const* d_in, const int* in_sizes, int n_in,
                              void* d_out, int out_size, void* d_ws, size_t ws_size,
                              hipStream_t stream) {
    const float* x  = (const float*)d_in[0];
    const float* W0 = (const float*)d_in[1];
    const float* W1 = (const float*)d_in[2];
    const float* W2 = (const float*)d_in[3];
    const float* b0 = (const float*)d_in[4];
    const float* b1 = (const float*)d_in[5];
    const float* b2 = (const float*)d_in[6];
    float* out = (float*)d_out;
    unsigned short* wt = (unsigned short*)d_ws;  // 117*8192*2 B = 1.87 MB

    const int prep_threads = NFT * 1024;         // 119808
    cin_prep<<<(prep_threads + 255) / 256, 256, 0, stream>>>(W0, W1, W2, wt);
    cin_mfma<<<1024 / BPB, 512, 0, stream>>>(x, wt, b0, b1, b2, out);
}

// Round 2
// 102.981 us; speedup vs baseline: 1.1330x; 1.0438x over previous
//
#include <hip/hip_runtime.h>

// CIN fused 3-layer, bf16 MFMA (R8).
// cur[sl,n] = sum_f x_f[sl] * S_f[sl,n],  S_f = sum_g h_g[sl] * W[f*64+g, n].
//
// R8 changes vs R7 (45 us, Occ 33%, MfmaUtil 27%):
//  - R7 diagnosis: L2 request path queue-saturated. 512 blocks x 1.87 MB
//    = 957 MB of 16B-granule L2 reads (21 TB/s, ~62% of ceiling);
//    per-wave effective load latency ~2700 cy (Little's law from
//    83 GB/s/CU with 96 KB nominal in-flight). More TLP makes it worse.
//  - Fix: halve demand at constant TLP. 256 blocks x 1024 thr, BPB=4,
//    16 waves = 8 n-tiles x 2 m-halves. B tiles staged to LDS ONCE per
//    block via global_load_lds (16B, linear layout = wt layout), waves
//    read B-frags from LDS. L2 demand 957 -> 479 MB.
//  - Phase structure (T3-lite): 39 phases x 3 tiles, LDS double buffer
//    2 x 48 KB, stage issued at phase START (issue-early/drain-late),
//    one __syncthreads per phase. 117 = 39*3 divides evenly; layer
//    boundaries fall on phase boundaries (13 phases/layer).
//
// wt layout (prep output), tile tl = l*39+f (layer0 g zero-padded):
//   wt[tl*8192 + ((ks*4 + q)*128 + n)*8 + j] = bf16(W_l[f*64 + ks*32+q*8+j][n])

#define NF      39
#define LCH     128
#define NLAYER  3
#define NFT     (NLAYER * NF)   // 117 f-tiles
#define BPB     4               // batches per block
#define SL      (BPB * 16)      // 64 slices per block
#define NTHR    1024
#define TILE_SH 8192            // shorts per B tile (16 KB)
#define PH_T    3               // tiles per phase
#define BUF_SH  (PH_T * TILE_SH) // 24576 shorts per buffer (48 KB)

typedef __bf16        bf16x8 __attribute__((ext_vector_type(8)));
typedef unsigned int  uint4v __attribute__((ext_vector_type(4)));
typedef float         f32x4  __attribute__((ext_vector_type(4)));

__device__ __forceinline__ unsigned short f2bf_rne(float f) {
    unsigned u = __float_as_uint(f);
    u += 0x7fffu + ((u >> 16) & 1u);
    return (unsigned short)(u >> 16);
}

// ---------------- prep: W fp32 -> bf16 frag-ready tiles in ws ----------------
__global__ void cin_prep(const float* __restrict__ W0,
                         const float* __restrict__ W1,
                         const float* __restrict__ W2,
                         unsigned short* __restrict__ wt)
{
    const int t = blockIdx.x * blockDim.x + threadIdx.x; // ((tl*2+ks)*4+q)*128 + n
    if (t >= NFT * 1024) return;
    const int n  = t & 127;
    const int q  = (t >> 7) & 3;
    const int ks = (t >> 9) & 1;
    const int tl = t >> 10;
    const int l  = tl / NF;
    const int f  = tl - l * NF;
    const float* W = (l == 0) ? W0 : (l == 1) ? W1 : W2;

    unsigned short v[8];
    #pragma unroll
    for (int j = 0; j < 8; ++j) {
        const int g = ks * 32 + q * 8 + j;
        float w = 0.0f;
        if (l == 0) { if (g < NF) w = W[(f * NF + g) * LCH + n]; }
        else        { w = W[(f * 64 + g) * LCH + n]; }
        v[j] = f2bf_rne(w);
    }
    uint4v pv;
    #pragma unroll
    for (int i = 0; i < 4; ++i)
        pv[i] = (unsigned)v[2 * i] | ((unsigned)v[2 * i + 1] << 16);
    ((uint4v*)wt)[t] = pv;   // 16B coalesced
}

// ---------------- main ----------------
__global__ __launch_bounds__(NTHR, 4) void cin_mfma(
    const float* __restrict__ x,
    const unsigned short* __restrict__ wt,
    const float* __restrict__ b0p,
    const float* __restrict__ b1p,
    const float* __restrict__ b2p,
    float* __restrict__ out)
{
    __shared__ __align__(16) unsigned short Bbuf[2 * BUF_SH];   // 96 KB B dbuf
    __shared__ __align__(16) unsigned short hfrag[8 * SL * 8];  // 8 KB
    __shared__ float xf32[NF * SL];                             // ~9.75 KB
    __shared__ float biasl[NLAYER * LCH];                       // 1.5 KB

    const int tid  = threadIdx.x;
    const int lane = tid & 63;
    const int w    = tid >> 6;      // wave 0..15
    const int wn   = w & 7;         // n-tile
    const int wm   = w >> 3;        // m-half: mt_g = wm*2 + {0,1}
    const int q    = lane >> 4;     // quad 0..3
    const int c    = lane & 15;
    const int nc   = wn * 16 + c;   // this lane's output channel
    const int bb   = blockIdx.x * BPB;

    // zero hfrag (covers layer-0 padding g in [39,64)): 8 KB = 512 * 16B
    if (tid < 512) {
        f32x4 z4 = {0.f, 0.f, 0.f, 0.f};
        ((f32x4*)hfrag)[tid] = z4;
    }
    if (tid < NLAYER * LCH)
        biasl[tid] = (tid < 128) ? b0p[tid] : (tid < 256) ? b1p[tid - 128] : b2p[tid - 256];
    __syncthreads();

    // stage x (contiguous BPB*NF*16 = 2496 floats for this block's batches)
    for (int i = tid; i < BPB * NF * 16; i += NTHR) {
        const float v = x[bb * (NF * 16) + i];
        const int lb = i / (NF * 16);
        const int r  = i - lb * (NF * 16);
        const int f  = r >> 4;
        const int d  = r & 15;
        const int sl = lb * 16 + d;
        xf32[f * SL + sl] = v;
        hfrag[((f >> 3) * SL + sl) * 8 + (f & 7)] = f2bf_rne(v);
    }

    // issue initial B staging: tiles 0..2 -> buf0 (16 waves x 1 KB per tile)
    {
        const unsigned short* src = wt + w * 512 + lane * 8;
        unsigned short* dst = Bbuf + w * 512;
        #pragma unroll
        for (int k = 0; k < PH_T; ++k)
            __builtin_amdgcn_global_load_lds((const void*)(src + k * TILE_SH),
                                             (void*)(dst + k * TILE_SH), 16, 0, 0);
    }
    __syncthreads();   // x, hfrag, bias, buf0 ready

    // per-lane B-frag read base within a tile (shorts)
    const unsigned short* bq = Bbuf + (q * 128 + nc) * 8;

    int cb = 0;   // current compute buffer
    int tl = 0;   // global tile index of current phase base

    #pragma unroll 1
    for (int l = 0; l < NLAYER; ++l) {
        // hoist A-frags (h) for this layer (literal indices only)
        bf16x8 a[2][2];
        #pragma unroll
        for (int ks = 0; ks < 2; ++ks)
            #pragma unroll
            for (int mtl = 0; mtl < 2; ++mtl)
                a[ks][mtl] = *(const bf16x8*)
                    &hfrag[((ks * 4 + q) * SL + (wm * 2 + mtl) * 16 + c) * 8];

        f32x4 cur0 = {0.f, 0.f, 0.f, 0.f};
        f32x4 cur1 = {0.f, 0.f, 0.f, 0.f};
        const f32x4 z = {0.f, 0.f, 0.f, 0.f};

        #pragma unroll 1
        for (int ph = 0; ph < NF / PH_T; ++ph) {
            // issue next phase's staging first (issue-early / drain-late)
            const int nb = tl + PH_T;
            if (nb < NFT) {
                const unsigned short* src = wt + (size_t)nb * TILE_SH + w * 512 + lane * 8;
                unsigned short* dst = &Bbuf[(cb ^ 1) * BUF_SH + w * 512];
                #pragma unroll
                for (int k = 0; k < PH_T; ++k)
                    __builtin_amdgcn_global_load_lds((const void*)(src + k * TILE_SH),
                                                     (void*)(dst + k * TILE_SH), 16, 0, 0);
            }

            // B-frag reads for this phase's 3 tiles (from LDS)
            const unsigned short* rb = bq + cb * BUF_SH;
            const bf16x8 B00 = *(const bf16x8*)(rb);
            const bf16x8 B01 = *(const bf16x8*)(rb + 4096);
            const bf16x8 B10 = *(const bf16x8*)(rb + TILE_SH);
            const bf16x8 B11 = *(const bf16x8*)(rb + TILE_SH + 4096);
            const bf16x8 B20 = *(const bf16x8*)(rb + 2 * TILE_SH);
            const bf16x8 B21 = *(const bf16x8*)(rb + 2 * TILE_SH + 4096);

            const int f0 = ph * PH_T;
            #define CIN_ITER(BV0, BV1, FI)                                              \
            {                                                                           \
                f32x4 sv0 = __builtin_amdgcn_mfma_f32_16x16x32_bf16(a[0][0], BV0, z, 0, 0, 0); \
                sv0 = __builtin_amdgcn_mfma_f32_16x16x32_bf16(a[1][0], BV1, sv0, 0, 0, 0);     \
                f32x4 sv1 = __builtin_amdgcn_mfma_f32_16x16x32_bf16(a[0][1], BV0, z, 0, 0, 0); \
                sv1 = __builtin_amdgcn_mfma_f32_16x16x32_bf16(a[1][1], BV1, sv1, 0, 0, 0);     \
                const f32x4 xr0 = *(const f32x4*)&xf32[(FI) * SL + (wm * 2 + 0) * 16 + q * 4]; \
                const f32x4 xr1 = *(const f32x4*)&xf32[(FI) * SL + (wm * 2 + 1) * 16 + q * 4]; \
                _Pragma("unroll")                                                       \
                for (int r = 0; r < 4; ++r) {                                           \
                    cur0[r] = fmaf(xr0[r], sv0[r], cur0[r]);                            \
                    cur1[r] = fmaf(xr1[r], sv1[r], cur1[r]);                            \
                }                                                                       \
            }
            CIN_ITER(B00, B01, f0 + 0)
            CIN_ITER(B10, B11, f0 + 1)
            CIN_ITER(B20, B21, f0 + 2)
            #undef CIN_ITER

            __syncthreads();   // drain staging (own vmcnt) + buffer handoff
            cb ^= 1;
            tl += PH_T;
        }

        // ---------------- epilogue for layer l ----------------
        const float bias = biasl[l * LCH + nc];
        float v[2][4];
        #pragma unroll
        for (int r = 0; r < 4; ++r) {
            v[0][r] = fmaxf(cur0[r] + bias, 0.f);
            v[1][r] = fmaxf(cur1[r] + bias, 0.f);
        }

        if (l < 2 && wn < 4) {
            // h channels (nc < 64): write next layer's h (C row = q*4+r)
            #pragma unroll
            for (int mtl = 0; mtl < 2; ++mtl)
                #pragma unroll
                for (int r = 0; r < 4; ++r)
                    hfrag[((nc >> 3) * SL + (wm * 2 + mtl) * 16 + q * 4 + r) * 8 + (nc & 7)] =
                        f2bf_rne(v[mtl][r]);
        } else {
            // direct channels: reduce over d (= q*4+r) and store
            // l==0: nc 64..127 -> out 0..63 ; l==1: nc 64..127 -> out 64..127 ;
            // l==2: nc 0..127 -> out 128..255
            const int outcol = (l == 0) ? nc - 64 : (l == 1) ? nc : 128 + nc;
            #pragma unroll
            for (int mtl = 0; mtl < 2; ++mtl) {
                float sacc = v[mtl][0] + v[mtl][1] + v[mtl][2] + v[mtl][3];
                sacc += __shfl_xor(sacc, 16, 64);
                sacc += __shfl_xor(sacc, 32, 64);
                if (lane < 16) out[(bb + wm * 2 + mtl) * 256 + outcol] = sacc;
            }
        }
        if (l < 2) __syncthreads();   // h writes visible before next A-hoist
    }
}

extern "C" void kernel_launch(void* const* d_in, const int* in_sizes, int n_in,
                              void* d_out, int out_size, void* d_ws, size_t ws_size,
                              hipStream_t stream) {
    const float* x  = (const float*)d_in[0];
    const float* W0 = (const float*)d_in[1];
    const float* W1 = (const float*)d_in[2];
    const float* W2 = (const float*)d_in[3];
    const float* b0 = (const float*)d_in[4];
    const float* b1 = (const float*)d_in[5];
    const float* b2 = (const float*)d_in[6];
    float* out = (float*)d_out;
    unsigned short* wt = (unsigned short*)d_ws;  // 117*8192*2 B = 1.87 MB

    const int prep_threads = NFT * 1024;         // 119808
    cin_prep<<<(prep_threads + 255) / 256, 256, 0, stream>>>(W0, W1, W2, wt);
    cin_mfma<<<1024 / BPB, NTHR, 0, stream>>>(x, wt, b0, b1, b2, out);
}